// Round 14
// baseline (286.683 us; speedup 1.0000x reference)
//
#include <hip/hip_runtime.h>

#define NN 100000
#define NE 1600000
#define DD 128
#define BN_EPS 1e-5f

#define SBSH 8                         // log2(super-bucket size)
#define SBSZ 256                       // nodes per super-bucket
#define NSB ((NN + SBSZ - 1) / SBSZ)   // 391 super-buckets
#define CAPS 4608                      // slots per bucket (mean 4092 + ~8 sigma)
#define GRID_PS 1024                   // unified-role blocks (scatter then prep)
#define EPB ((NE + GRID_PS - 1) / GRID_PS)   // 1563 edges per block
#define BN_BLOCKS 1024

typedef __attribute__((ext_vector_type(8))) short short8;
typedef __attribute__((ext_vector_type(4))) float floatx4;

__device__ __forceinline__ unsigned short f2bf(float f) {
    union { float f; unsigned u; } v; v.f = f;
    return (unsigned short)((v.u + 0x7FFFu + ((v.u >> 16) & 1u)) >> 16);
}
__device__ __forceinline__ float bf2f(unsigned short u) {
    union { unsigned u; float f; } v; v.u = ((unsigned)u) << 16;
    return v.f;
}

// ---------------------------------------------------------------------------
// K1 (unified-role): EVERY block first scatters its 1563-edge share into the
// 391 super-buckets (LDS histogram -> chunk reservation -> direct scatter),
// then falls through to its grid-stride prep share (W->bf16 transpose +
// h->bf16 copy). R13 showed role-partitioned K1 ran its scatter tail at
// 2 blocks/CU, occ 26%, VALU 3.5%: the latency-bound chain had no cover.
// Unified roles double scatter TLP and overlap every scatter stall with
// prep streaming on the same CU. scnt zeroed by preceding memset.
// ---------------------------------------------------------------------------
__global__ __launch_bounds__(256) void prep_scatter_kernel(
    const float* __restrict__ W1, const float* __restrict__ W2,
    unsigned short* __restrict__ W1t, unsigned short* __restrict__ W2t,
    const float* __restrict__ h, unsigned short* __restrict__ hb, int do_hb,
    const int* __restrict__ src, const int* __restrict__ dst,
    int* __restrict__ scnt, int* __restrict__ sbuf)
{
    __shared__ int bins[512];
    int t = threadIdx.x;

    // ---- phase A: scatter this block's edge share ----
    bins[t] = 0; bins[t + 256] = 0;
    __syncthreads();
    int base = blockIdx.x * EPB;
    int ecnt = min(EPB, NE - base);
    for (int i = t; i < ecnt; i += 256)
        atomicAdd(&bins[dst[base + i] >> SBSH], 1);
    __syncthreads();
#pragma unroll
    for (int l = 0; l < 2; ++l) {
        int w = t + l * 256;
        int c = bins[w];
        int gb = (w < NSB && c) ? atomicAdd(&scnt[w], c) : 0;
        bins[w] = w * CAPS + gb;   // global chunk cursor for this block
    }
    __syncthreads();
    for (int i = t; i < ecnt; i += 256) {
        int d = dst[base + i];
        int p = atomicAdd(&bins[d >> SBSH], 1);
        sbuf[p] = (src[base + i] << SBSH) | (d & (SBSZ - 1));
    }

    // ---- phase B: prep share (disjoint data; no sync needed) ----
    int tid0 = blockIdx.x * 256 + t;
    int stride = GRID_PS * 256;
    for (int i = tid0; i < DD * DD; i += stride) {
        int n = i >> 7, k = i & 127;
        W1t[i] = f2bf(W1[k * DD + n]);
        W2t[i] = f2bf(W2[k * DD + n]);
    }
    if (do_hb) {
        const float4* h4 = (const float4*)h;
        ushort4* hb4 = (ushort4*)hb;
        for (int i = tid0; i < NN * (DD / 4); i += stride) {
            float4 v = h4[i];
            ushort4 o;
            o.x = f2bf(v.x); o.y = f2bf(v.y); o.z = f2bf(v.z); o.w = f2bf(v.w);
            hb4[i] = o;
        }
    }
}

// ---------------------------------------------------------------------------
// K2: per-super-bucket CSR permute. 391 blocks x 512 thr (18.4KB LDS) over
// all 256 CUs: stage ~4.1K edges, count+scan 256 node bins, write
// off2[node]={beg,end} absolute, in-place permute (single-writer region).
// ---------------------------------------------------------------------------
__global__ __launch_bounds__(512) void permute_kernel(
    const int* __restrict__ scnt, int* __restrict__ sbuf,
    int2* __restrict__ off2)
{
    __shared__ int ew[CAPS];          // 18432 B
    __shared__ int cnt[SBSZ];
    __shared__ int cur[SBSZ];
    __shared__ int stmp[SBSZ];
    int sb = blockIdx.x, t = threadIdx.x;
    if (t < SBSZ) cnt[t] = 0;
    __syncthreads();
    int n = min(scnt[sb], CAPS);
    int sbase = sb * CAPS;
    for (int i = t; i < n; i += 512) {
        int e = sbuf[sbase + i];
        ew[i] = e;
        atomicAdd(&cnt[e & (SBSZ - 1)], 1);
    }
    __syncthreads();
    int c = 0;
    if (t < SBSZ) { c = cnt[t]; stmp[t] = c; }
    __syncthreads();
#pragma unroll
    for (int ofs = 1; ofs < SBSZ; ofs <<= 1) {
        int u = (t < SBSZ && t >= ofs) ? stmp[t - ofs] : 0;
        __syncthreads();
        if (t < SBSZ) stmp[t] += u;
        __syncthreads();
    }
    if (t < SBSZ) {
        int excl = stmp[t] - c;
        cur[t] = excl;
        off2[sb * SBSZ + t] = make_int2(sbase + excl, sbase + excl + c);
    }
    __syncthreads();
    for (int i = t; i < n; i += 512) {
        int e = ew[i];
        int p = atomicAdd(&cur[e & (SBSZ - 1)], 1);
        sbuf[sbase + p] = e >> SBSH;   // in place (staged in LDS)
    }
}

// ---------------------------------------------------------------------------
// K3: gather, single dispatch (R11-proven 65us config: 16 lanes/node,
// unroll-4, no LDS, ~70% occupancy).
// ---------------------------------------------------------------------------
__global__ __launch_bounds__(256) void gather_bf16_kernel(
    const float* __restrict__ h, const unsigned short* __restrict__ hb,
    const float* __restrict__ eps, const int2* __restrict__ off2,
    const int* __restrict__ srcs, unsigned short* __restrict__ xb)
{
    int node = blockIdx.x * 16 + (threadIdx.x >> 4);
    if (node >= NN) return;
    int c8 = threadIdx.x & 15;
    const float s = 1.0f + eps[0];
    const float4* h4 = (const float4*)h;
    float4 a0 = h4[node * 32 + c8 * 2];
    float4 a1 = h4[node * 32 + c8 * 2 + 1];
    float acc[8] = {s * a0.x, s * a0.y, s * a0.z, s * a0.w,
                    s * a1.x, s * a1.y, s * a1.z, s * a1.w};
    int2 oo = off2[node];
    int e = oo.x, eend = oo.y;
    const short8* hb8 = (const short8*)hb;
    for (; e + 3 < eend; e += 4) {
        int s0 = srcs[e],     s1 = srcs[e + 1];
        int s2 = srcs[e + 2], s3 = srcs[e + 3];
        short8 v0 = hb8[s0 * 16 + c8];
        short8 v1 = hb8[s1 * 16 + c8];
        short8 v2 = hb8[s2 * 16 + c8];
        short8 v3 = hb8[s3 * 16 + c8];
#pragma unroll
        for (int j = 0; j < 8; ++j) {
            float t0 = bf2f((unsigned short)v0[j]) + bf2f((unsigned short)v1[j]);
            float t1 = bf2f((unsigned short)v2[j]) + bf2f((unsigned short)v3[j]);
            acc[j] += t0 + t1;
        }
    }
    for (; e < eend; ++e) {
        short8 v0 = hb8[srcs[e] * 16 + c8];
#pragma unroll
        for (int j = 0; j < 8; ++j) acc[j] += bf2f((unsigned short)v0[j]);
    }
    short8 o;
#pragma unroll
    for (int j = 0; j < 8; ++j) o[j] = (short)f2bf(acc[j]);
    ((short8*)xb)[node * 16 + c8] = o;
}

__global__ __launch_bounds__(256) void gather_f32_kernel(
    const float* __restrict__ h, const float* __restrict__ eps,
    const int2* __restrict__ off2, const int* __restrict__ srcs,
    unsigned short* __restrict__ xb)
{
    int node = blockIdx.x * 16 + (threadIdx.x >> 4);
    if (node >= NN) return;
    int c8 = threadIdx.x & 15;
    const float4* h4 = (const float4*)h;
    const float s = 1.0f + eps[0];
    float4 a0 = h4[node * 32 + c8 * 2];
    float4 a1 = h4[node * 32 + c8 * 2 + 1];
    float acc[8] = {s * a0.x, s * a0.y, s * a0.z, s * a0.w,
                    s * a1.x, s * a1.y, s * a1.z, s * a1.w};
    int2 oo = off2[node];
    int e = oo.x, eend = oo.y;
    for (; e + 1 < eend; e += 2) {
        int s0 = srcs[e], s1 = srcs[e + 1];
        float4 u0 = h4[s0 * 32 + c8 * 2], u1 = h4[s0 * 32 + c8 * 2 + 1];
        float4 w0 = h4[s1 * 32 + c8 * 2], w1 = h4[s1 * 32 + c8 * 2 + 1];
        acc[0] += u0.x + w0.x; acc[1] += u0.y + w0.y;
        acc[2] += u0.z + w0.z; acc[3] += u0.w + w0.w;
        acc[4] += u1.x + w1.x; acc[5] += u1.y + w1.y;
        acc[6] += u1.z + w1.z; acc[7] += u1.w + w1.w;
    }
    if (e < eend) {
        int s0 = srcs[e];
        float4 u0 = h4[s0 * 32 + c8 * 2], u1 = h4[s0 * 32 + c8 * 2 + 1];
        acc[0] += u0.x; acc[1] += u0.y; acc[2] += u0.z; acc[3] += u0.w;
        acc[4] += u1.x; acc[5] += u1.y; acc[6] += u1.z; acc[7] += u1.w;
    }
    short8 o;
#pragma unroll
    for (int j = 0; j < 8; ++j) o[j] = (short)f2bf(acc[j]);
    ((short8*)xb)[node * 16 + c8] = o;
}

// ---------------------------------------------------------------------------
// K4: fused 2-layer MLP + BN stats, 128-row / 512-thread tile (R10/R11-
// proven). W staged once per layer per 128 rows.
// ---------------------------------------------------------------------------
__global__ __launch_bounds__(512) void mlp_fused_kernel(
    const unsigned short* __restrict__ X,
    const unsigned short* __restrict__ W1t, const unsigned short* __restrict__ W2t,
    const float* __restrict__ b1, const float* __restrict__ b2,
    unsigned short* __restrict__ Y, float* __restrict__ stats)
{
    extern __shared__ char smem[];
    unsigned short* wl = (unsigned short*)smem;            // [128][136] bf16
    unsigned short* xl = (unsigned short*)(smem + 34816);  // [128][136] bf16

    const int tid = threadIdx.x;
    const int r0 = blockIdx.x * 128;
    const int lane = tid & 63;
    const int wv = tid >> 6;        // 0..7: wave's 16-row band
    const int m = lane & 15;
    const int hi = lane >> 4;

    const short8* W18 = (const short8*)W1t;
#pragma unroll
    for (int l = 0; l < 4; ++l) {
        int idx = tid + l * 512;
        int n = idx >> 4, c = idx & 15;
        *(short8*)&wl[n * 136 + c * 8] = W18[idx];
    }
    const short8* X8 = (const short8*)X;
#pragma unroll
    for (int l = 0; l < 4; ++l) {
        int idx = tid + l * 512;
        int row = idx >> 4, c = idx & 15;
        int g = r0 + row;
        short8 v = {0, 0, 0, 0, 0, 0, 0, 0};
        if (g < NN) v = X8[g * 16 + c];
        *(short8*)&xl[row * 136 + c * 8] = v;
    }
    __syncthreads();

    floatx4 acc[8];
#pragma unroll
    for (int i = 0; i < 8; ++i) acc[i] = (floatx4){0.f, 0.f, 0.f, 0.f};
#pragma unroll
    for (int kc = 0; kc < 4; ++kc) {
        short8 a = *(const short8*)&xl[(wv * 16 + m) * 136 + kc * 32 + hi * 8];
#pragma unroll
        for (int nt = 0; nt < 8; ++nt) {
            short8 b = *(const short8*)&wl[(nt * 16 + m) * 136 + kc * 32 + hi * 8];
            acc[nt] = __builtin_amdgcn_mfma_f32_16x16x32_bf16(a, b, acc[nt], 0, 0, 0);
        }
    }
    __syncthreads();

#pragma unroll
    for (int nt = 0; nt < 8; ++nt) {
        float bv = b1[nt * 16 + m];
#pragma unroll
        for (int r = 0; r < 4; ++r) {
            float v = fmaxf(acc[nt][r] + bv, 0.f);
            xl[(wv * 16 + hi * 4 + r) * 136 + nt * 16 + m] = f2bf(v);
        }
    }
    const short8* W28 = (const short8*)W2t;
#pragma unroll
    for (int l = 0; l < 4; ++l) {
        int idx = tid + l * 512;
        int n = idx >> 4, c = idx & 15;
        *(short8*)&wl[n * 136 + c * 8] = W28[idx];
    }
    __syncthreads();

#pragma unroll
    for (int i = 0; i < 8; ++i) acc[i] = (floatx4){0.f, 0.f, 0.f, 0.f};
#pragma unroll
    for (int kc = 0; kc < 4; ++kc) {
        short8 a = *(const short8*)&xl[(wv * 16 + m) * 136 + kc * 32 + hi * 8];
#pragma unroll
        for (int nt = 0; nt < 8; ++nt) {
            short8 b = *(const short8*)&wl[(nt * 16 + m) * 136 + kc * 32 + hi * 8];
            acc[nt] = __builtin_amdgcn_mfma_f32_16x16x32_bf16(a, b, acc[nt], 0, 0, 0);
        }
    }
    __syncthreads();

#pragma unroll
    for (int nt = 0; nt < 8; ++nt) {
        float bv = b2[nt * 16 + m];
#pragma unroll
        for (int r = 0; r < 4; ++r) {
            float v = acc[nt][r] + bv;
            xl[(wv * 16 + hi * 4 + r) * 136 + nt * 16 + m] = f2bf(v);
        }
    }
    __syncthreads();

#pragma unroll
    for (int l = 0; l < 4; ++l) {
        int idx = tid + l * 512;
        int row = idx >> 4, c = idx & 15;
        int g = r0 + row;
        if (g < NN)
            ((short8*)Y)[g * 16 + c] = *(const short8*)&xl[row * 136 + c * 8];
    }

    int col = tid & 127, quarter = tid >> 7;
    int rlim = min(128, NN - r0);
    int rbeg = quarter * 32, rend = min(rbeg + 32, rlim);
    float s = 0.f, q = 0.f;
    for (int r = rbeg; r < rend; ++r) {
        float v = bf2f(xl[r * 136 + col]);
        s += v; q += v * v;
    }
    float* red = (float*)wl;        // wl dead after GEMM2
    red[tid] = s;
    red[512 + tid] = q;
    __syncthreads();
    if (tid < 128) {
        float ts = red[tid] + red[128 + tid] + red[256 + tid] + red[384 + tid];
        float tq = red[512 + tid] + red[640 + tid] + red[768 + tid] + red[896 + tid];
        atomicAdd(&stats[tid], ts);
        atomicAdd(&stats[DD + tid], tq);
    }
}

// ---------------------------------------------------------------------------
// K5: out = h + relu(Y*scale + shift). BN math hoisted (column octet fixed).
// ---------------------------------------------------------------------------
__global__ __launch_bounds__(256) void bn_final_kernel(
    const unsigned short* __restrict__ Y, const float* __restrict__ h,
    const float* __restrict__ gamma, const float* __restrict__ beta,
    const float* __restrict__ stats, float* __restrict__ out)
{
    const float invN = 1.0f / (float)NN;
    int t0 = blockIdx.x * 256 + threadIdx.x;
    int c8 = t0 & 15;
    float sc[8], sh[8];
#pragma unroll
    for (int j = 0; j < 8; ++j) {
        int col = c8 * 8 + j;
        float mu = stats[col] * invN;
        float var = stats[DD + col] * invN - mu * mu;
        float s = rsqrtf(var + BN_EPS) * gamma[col];
        sc[j] = s;
        sh[j] = beta[col] - mu * s;
    }
    const short8* Y8 = (const short8*)Y;
    const float4* H4 = (const float4*)h;
    float4* O4 = (float4*)out;
    const int total = NN * 16;
    const int stride = BN_BLOCKS * 256;
    for (int i = t0; i < total; i += stride) {
        short8 u = Y8[i];
        float4 h0 = H4[2 * i], h1 = H4[2 * i + 1];
        float4 r0, r1;
        r0.x = h0.x + fmaxf(bf2f((unsigned short)u[0]) * sc[0] + sh[0], 0.f);
        r0.y = h0.y + fmaxf(bf2f((unsigned short)u[1]) * sc[1] + sh[1], 0.f);
        r0.z = h0.z + fmaxf(bf2f((unsigned short)u[2]) * sc[2] + sh[2], 0.f);
        r0.w = h0.w + fmaxf(bf2f((unsigned short)u[3]) * sc[3] + sh[3], 0.f);
        r1.x = h1.x + fmaxf(bf2f((unsigned short)u[4]) * sc[4] + sh[4], 0.f);
        r1.y = h1.y + fmaxf(bf2f((unsigned short)u[5]) * sc[5] + sh[5], 0.f);
        r1.z = h1.z + fmaxf(bf2f((unsigned short)u[6]) * sc[6] + sh[6], 0.f);
        r1.w = h1.w + fmaxf(bf2f((unsigned short)u[7]) * sc[7] + sh[7], 0.f);
        O4[2 * i] = r0;
        O4[2 * i + 1] = r1;
    }
}

// ---------------------------------------------------------------------------
extern "C" void kernel_launch(void* const* d_in, const int* in_sizes, int n_in,
                              void* d_out, int out_size, void* d_ws, size_t ws_size,
                              hipStream_t stream)
{
    const float* h     = (const float*)d_in[0];
    const int*   src   = (const int*)d_in[1];
    const int*   dst   = (const int*)d_in[2];
    const float* eps   = (const float*)d_in[3];
    const float* W1    = (const float*)d_in[4];
    const float* b1    = (const float*)d_in[5];
    const float* W2    = (const float*)d_in[6];
    const float* b2    = (const float*)d_in[7];
    const float* gamma = (const float*)d_in[8];
    const float* beta  = (const float*)d_in[9];
    float* out = (float*)d_out;

    char* w = (char*)d_ws;
    size_t o = 0;
    float* stats    = (float*)(w + o); o += 256 * 4;                 // memset
    int* scnt       = (int*)(w + o); o += 1024 * 4;                  // memset (391 used)
    unsigned short* W1t = (unsigned short*)(w + o); o += (size_t)DD * DD * 2;
    unsigned short* W2t = (unsigned short*)(w + o); o += (size_t)DD * DD * 2;
    int2* off2      = (int2*)(w + o); o += (size_t)NSB * SBSZ * 8;   // 800768
    int* sbuf       = (int*)(w + o); o += (size_t)NSB * CAPS * 4;    // 7.2 MB
    unsigned short* xb  = (unsigned short*)(w + o); o += (size_t)NN * DD * 2;
    unsigned short* hb  = (unsigned short*)(w + o); o += (size_t)NN * DD * 2;
    const int use_hb = (ws_size >= o) ? 1 : 0;  // launch-constant

    // 0. zero stats + super-bucket cursors (contiguous 5 KB)
    hipMemsetAsync(stats, 0, (256 + 1024) * sizeof(int), stream);

    // 1. unified-role prep+scatter (all 1024 blocks do scatter then prep)
    prep_scatter_kernel<<<GRID_PS, 256, 0, stream>>>(
        W1, W2, W1t, W2t, h, hb, use_hb, src, dst, scnt, sbuf);

    // 2. per-super-bucket CSR permute (391 blocks x 512 thr)
    permute_kernel<<<NSB, 512, 0, stream>>>(scnt, sbuf, off2);

    // 3. gather (single dispatch, R11-proven config)
    if (use_hb)
        gather_bf16_kernel<<<(NN + 15) / 16, 256, 0, stream>>>(h, hb, eps, off2, sbuf, xb);
    else
        gather_f32_kernel<<<(NN + 15) / 16, 256, 0, stream>>>(h, eps, off2, sbuf, xb);

    // 4. fused 2-layer MLP + BN stats (128-row / 512-thread tile)
    size_t gemm_lds = 69632;
    mlp_fused_kernel<<<(NN + 127) / 128, 512, gemm_lds, stream>>>(
        xb, W1t, W2t, b1, b2, xb, stats);

    // 5. out = h + relu(BN(y2))
    bn_final_kernel<<<BN_BLOCKS, 256, 0, stream>>>(xb, h, gamma, beta, stats, out);
}

// Round 15
// 268.619 us; speedup vs baseline: 1.0672x; 1.0672x over previous
//
#include <hip/hip_runtime.h>

#define NN 100000
#define NE 1600000
#define DD 128
#define BN_EPS 1e-5f

#define SBSH 9                         // log2(super-bucket size)
#define SBSZ 512                       // nodes per super-bucket
#define NSB ((NN + SBSZ - 1) / SBSZ)   // 196 super-buckets
#define CAPS 9216                      // slots per bucket (mean 8163 + ~11 sigma)
#define SCATBLKS 512                   // scatter-role blocks (R11-proven)
#define EPB ((NE + SCATBLKS - 1) / SCATBLKS)   // 3125 edges/block
#define PREPBLKS 64                    // W-transpose only (hb copy moved to K2)
#define GRID_PS (SCATBLKS + PREPBLKS)  // 576
#define COPYBLKS 128                   // hb-copy role blocks in K2
#define BN_BLOCKS 1024

typedef __attribute__((ext_vector_type(8))) short short8;
typedef __attribute__((ext_vector_type(4))) float floatx4;

__device__ __forceinline__ unsigned short f2bf(float f) {
    union { float f; unsigned u; } v; v.f = f;
    return (unsigned short)((v.u + 0x7FFFu + ((v.u >> 16) & 1u)) >> 16);
}
__device__ __forceinline__ float bf2f(unsigned short u) {
    union { unsigned u; float f; } v; v.u = ((unsigned)u) << 16;
    return v.f;
}

// ---------------------------------------------------------------------------
// K1: blocks [0,512) = super-bucket radix scatter (R11-proven: LDS histogram
// -> chunk reservation -> direct scatter, ~16-int chunks); blocks [512,576)
// = W->bf16 transpose only. The h->bf16 copy moved to K2 (pipeline-stage
// rebalance: K2 left 60 CUs idle while K1 carried ~14us of independent
// streaming). scnt zeroed by preceding memset.
// ---------------------------------------------------------------------------
__global__ __launch_bounds__(256) void prep_scatter_kernel(
    const float* __restrict__ W1, const float* __restrict__ W2,
    unsigned short* __restrict__ W1t, unsigned short* __restrict__ W2t,
    const int* __restrict__ src, const int* __restrict__ dst,
    int* __restrict__ scnt, int* __restrict__ sbuf)
{
    __shared__ int bins[256];
    int t = threadIdx.x;

    if (blockIdx.x < SCATBLKS) {
        bins[t] = 0;
        __syncthreads();
        int base = blockIdx.x * EPB;
        int ecnt = min(EPB, NE - base);
        for (int i = t; i < ecnt; i += 256)
            atomicAdd(&bins[dst[base + i] >> SBSH], 1);
        __syncthreads();
        int c = bins[t];
        int gb = (t < NSB && c) ? atomicAdd(&scnt[t], c) : 0;
        __syncthreads();
        bins[t] = t * CAPS + gb;   // global chunk cursor for this block
        __syncthreads();
        for (int i = t; i < ecnt; i += 256) {
            int d = dst[base + i];
            int p = atomicAdd(&bins[d >> SBSH], 1);
            sbuf[p] = (src[base + i] << SBSH) | (d & (SBSZ - 1));
        }
    } else {
        int tid0 = (blockIdx.x - SCATBLKS) * 256 + t;
        int stride = PREPBLKS * 256;
        for (int i = tid0; i < DD * DD; i += stride) {
            int n = i >> 7, k = i & 127;
            W1t[i] = f2bf(W1[k * DD + n]);
            W2t[i] = f2bf(W2[k * DD + n]);
        }
    }
}

// ---------------------------------------------------------------------------
// K2: blocks [0,196) = per-super-bucket CSR permute (R11-proven: 1024 thr,
// LDS stage ~8.2K edges, count+scan 512 node bins, off2={beg,end} absolute,
// in-place permute). Blocks [196,324) = h->bf16 copy (fills the 60 CUs the
// permute leaves idle; independent of scatter output).
// ---------------------------------------------------------------------------
__global__ __launch_bounds__(1024) void permute_copy_kernel(
    const int* __restrict__ scnt, int* __restrict__ sbuf,
    int2* __restrict__ off2,
    const float* __restrict__ h, unsigned short* __restrict__ hb, int do_hb)
{
    __shared__ int ew[CAPS];          // 36864 B
    __shared__ int cnt[SBSZ];
    __shared__ int cur[SBSZ];
    __shared__ int stmp[SBSZ];
    int sb = blockIdx.x, t = threadIdx.x;

    if (sb < NSB) {
        if (t < SBSZ) cnt[t] = 0;
        __syncthreads();
        int n = min(scnt[sb], CAPS);
        int sbase = sb * CAPS;
        for (int i = t; i < n; i += 1024) {
            int e = sbuf[sbase + i];
            ew[i] = e;
            atomicAdd(&cnt[e & (SBSZ - 1)], 1);
        }
        __syncthreads();
        int c = 0;
        if (t < SBSZ) { c = cnt[t]; stmp[t] = c; }
        __syncthreads();
#pragma unroll
        for (int ofs = 1; ofs < SBSZ; ofs <<= 1) {
            int u = (t < SBSZ && t >= ofs) ? stmp[t - ofs] : 0;
            __syncthreads();
            if (t < SBSZ) stmp[t] += u;
            __syncthreads();
        }
        if (t < SBSZ) {
            int excl = stmp[t] - c;
            cur[t] = excl;
            off2[sb * SBSZ + t] = make_int2(sbase + excl, sbase + excl + c);
        }
        __syncthreads();
        for (int i = t; i < n; i += 1024) {
            int e = ew[i];
            int p = atomicAdd(&cur[e & (SBSZ - 1)], 1);
            sbuf[sbase + p] = e >> SBSH;   // in place (staged in LDS)
        }
    } else if (do_hb) {
        int tid0 = (sb - NSB) * 1024 + t;
        int stride = COPYBLKS * 1024;
        const float4* h4 = (const float4*)h;
        ushort4* hb4 = (ushort4*)hb;
        for (int i = tid0; i < NN * (DD / 4); i += stride) {
            float4 v = h4[i];
            ushort4 o;
            o.x = f2bf(v.x); o.y = f2bf(v.y); o.z = f2bf(v.z); o.w = f2bf(v.w);
            hb4[i] = o;
        }
    }
}

// ---------------------------------------------------------------------------
// K3: gather (R11-proven 65us config: 16 lanes/node, unroll-4, no LDS).
// ---------------------------------------------------------------------------
__global__ __launch_bounds__(256) void gather_bf16_kernel(
    const float* __restrict__ h, const unsigned short* __restrict__ hb,
    const float* __restrict__ eps, const int2* __restrict__ off2,
    const int* __restrict__ srcs, unsigned short* __restrict__ xb)
{
    int node = blockIdx.x * 16 + (threadIdx.x >> 4);
    if (node >= NN) return;
    int c8 = threadIdx.x & 15;
    const float s = 1.0f + eps[0];
    const float4* h4 = (const float4*)h;
    float4 a0 = h4[node * 32 + c8 * 2];
    float4 a1 = h4[node * 32 + c8 * 2 + 1];
    float acc[8] = {s * a0.x, s * a0.y, s * a0.z, s * a0.w,
                    s * a1.x, s * a1.y, s * a1.z, s * a1.w};
    int2 oo = off2[node];
    int e = oo.x, eend = oo.y;
    const short8* hb8 = (const short8*)hb;
    for (; e + 3 < eend; e += 4) {
        int s0 = srcs[e],     s1 = srcs[e + 1];
        int s2 = srcs[e + 2], s3 = srcs[e + 3];
        short8 v0 = hb8[s0 * 16 + c8];
        short8 v1 = hb8[s1 * 16 + c8];
        short8 v2 = hb8[s2 * 16 + c8];
        short8 v3 = hb8[s3 * 16 + c8];
#pragma unroll
        for (int j = 0; j < 8; ++j) {
            float t0 = bf2f((unsigned short)v0[j]) + bf2f((unsigned short)v1[j]);
            float t1 = bf2f((unsigned short)v2[j]) + bf2f((unsigned short)v3[j]);
            acc[j] += t0 + t1;
        }
    }
    for (; e < eend; ++e) {
        short8 v0 = hb8[srcs[e] * 16 + c8];
#pragma unroll
        for (int j = 0; j < 8; ++j) acc[j] += bf2f((unsigned short)v0[j]);
    }
    short8 o;
#pragma unroll
    for (int j = 0; j < 8; ++j) o[j] = (short)f2bf(acc[j]);
    ((short8*)xb)[node * 16 + c8] = o;
}

__global__ __launch_bounds__(256) void gather_f32_kernel(
    const float* __restrict__ h, const float* __restrict__ eps,
    const int2* __restrict__ off2, const int* __restrict__ srcs,
    unsigned short* __restrict__ xb)
{
    int node = blockIdx.x * 16 + (threadIdx.x >> 4);
    if (node >= NN) return;
    int c8 = threadIdx.x & 15;
    const float4* h4 = (const float4*)h;
    const float s = 1.0f + eps[0];
    float4 a0 = h4[node * 32 + c8 * 2];
    float4 a1 = h4[node * 32 + c8 * 2 + 1];
    float acc[8] = {s * a0.x, s * a0.y, s * a0.z, s * a0.w,
                    s * a1.x, s * a1.y, s * a1.z, s * a1.w};
    int2 oo = off2[node];
    int e = oo.x, eend = oo.y;
    for (; e + 1 < eend; e += 2) {
        int s0 = srcs[e], s1 = srcs[e + 1];
        float4 u0 = h4[s0 * 32 + c8 * 2], u1 = h4[s0 * 32 + c8 * 2 + 1];
        float4 w0 = h4[s1 * 32 + c8 * 2], w1 = h4[s1 * 32 + c8 * 2 + 1];
        acc[0] += u0.x + w0.x; acc[1] += u0.y + w0.y;
        acc[2] += u0.z + w0.z; acc[3] += u0.w + w0.w;
        acc[4] += u1.x + w1.x; acc[5] += u1.y + w1.y;
        acc[6] += u1.z + w1.z; acc[7] += u1.w + w1.w;
    }
    if (e < eend) {
        int s0 = srcs[e];
        float4 u0 = h4[s0 * 32 + c8 * 2], u1 = h4[s0 * 32 + c8 * 2 + 1];
        acc[0] += u0.x; acc[1] += u0.y; acc[2] += u0.z; acc[3] += u0.w;
        acc[4] += u1.x; acc[5] += u1.y; acc[6] += u1.z; acc[7] += u1.w;
    }
    short8 o;
#pragma unroll
    for (int j = 0; j < 8; ++j) o[j] = (short)f2bf(acc[j]);
    ((short8*)xb)[node * 16 + c8] = o;
}

// ---------------------------------------------------------------------------
// K4: fused 2-layer MLP + BN stats, 128-row / 512-thread tile (R10/R11-
// proven). W staged once per layer per 128 rows.
// ---------------------------------------------------------------------------
__global__ __launch_bounds__(512) void mlp_fused_kernel(
    const unsigned short* __restrict__ X,
    const unsigned short* __restrict__ W1t, const unsigned short* __restrict__ W2t,
    const float* __restrict__ b1, const float* __restrict__ b2,
    unsigned short* __restrict__ Y, float* __restrict__ stats)
{
    extern __shared__ char smem[];
    unsigned short* wl = (unsigned short*)smem;            // [128][136] bf16
    unsigned short* xl = (unsigned short*)(smem + 34816);  // [128][136] bf16

    const int tid = threadIdx.x;
    const int r0 = blockIdx.x * 128;
    const int lane = tid & 63;
    const int wv = tid >> 6;        // 0..7: wave's 16-row band
    const int m = lane & 15;
    const int hi = lane >> 4;

    const short8* W18 = (const short8*)W1t;
#pragma unroll
    for (int l = 0; l < 4; ++l) {
        int idx = tid + l * 512;
        int n = idx >> 4, c = idx & 15;
        *(short8*)&wl[n * 136 + c * 8] = W18[idx];
    }
    const short8* X8 = (const short8*)X;
#pragma unroll
    for (int l = 0; l < 4; ++l) {
        int idx = tid + l * 512;
        int row = idx >> 4, c = idx & 15;
        int g = r0 + row;
        short8 v = {0, 0, 0, 0, 0, 0, 0, 0};
        if (g < NN) v = X8[g * 16 + c];
        *(short8*)&xl[row * 136 + c * 8] = v;
    }
    __syncthreads();

    floatx4 acc[8];
#pragma unroll
    for (int i = 0; i < 8; ++i) acc[i] = (floatx4){0.f, 0.f, 0.f, 0.f};
#pragma unroll
    for (int kc = 0; kc < 4; ++kc) {
        short8 a = *(const short8*)&xl[(wv * 16 + m) * 136 + kc * 32 + hi * 8];
#pragma unroll
        for (int nt = 0; nt < 8; ++nt) {
            short8 b = *(const short8*)&wl[(nt * 16 + m) * 136 + kc * 32 + hi * 8];
            acc[nt] = __builtin_amdgcn_mfma_f32_16x16x32_bf16(a, b, acc[nt], 0, 0, 0);
        }
    }
    __syncthreads();

#pragma unroll
    for (int nt = 0; nt < 8; ++nt) {
        float bv = b1[nt * 16 + m];
#pragma unroll
        for (int r = 0; r < 4; ++r) {
            float v = fmaxf(acc[nt][r] + bv, 0.f);
            xl[(wv * 16 + hi * 4 + r) * 136 + nt * 16 + m] = f2bf(v);
        }
    }
    const short8* W28 = (const short8*)W2t;
#pragma unroll
    for (int l = 0; l < 4; ++l) {
        int idx = tid + l * 512;
        int n = idx >> 4, c = idx & 15;
        *(short8*)&wl[n * 136 + c * 8] = W28[idx];
    }
    __syncthreads();

#pragma unroll
    for (int i = 0; i < 8; ++i) acc[i] = (floatx4){0.f, 0.f, 0.f, 0.f};
#pragma unroll
    for (int kc = 0; kc < 4; ++kc) {
        short8 a = *(const short8*)&xl[(wv * 16 + m) * 136 + kc * 32 + hi * 8];
#pragma unroll
        for (int nt = 0; nt < 8; ++nt) {
            short8 b = *(const short8*)&wl[(nt * 16 + m) * 136 + kc * 32 + hi * 8];
            acc[nt] = __builtin_amdgcn_mfma_f32_16x16x32_bf16(a, b, acc[nt], 0, 0, 0);
        }
    }
    __syncthreads();

#pragma unroll
    for (int nt = 0; nt < 8; ++nt) {
        float bv = b2[nt * 16 + m];
#pragma unroll
        for (int r = 0; r < 4; ++r) {
            float v = acc[nt][r] + bv;
            xl[(wv * 16 + hi * 4 + r) * 136 + nt * 16 + m] = f2bf(v);
        }
    }
    __syncthreads();

#pragma unroll
    for (int l = 0; l < 4; ++l) {
        int idx = tid + l * 512;
        int row = idx >> 4, c = idx & 15;
        int g = r0 + row;
        if (g < NN)
            ((short8*)Y)[g * 16 + c] = *(const short8*)&xl[row * 136 + c * 8];
    }

    int col = tid & 127, quarter = tid >> 7;
    int rlim = min(128, NN - r0);
    int rbeg = quarter * 32, rend = min(rbeg + 32, rlim);
    float s = 0.f, q = 0.f;
    for (int r = rbeg; r < rend; ++r) {
        float v = bf2f(xl[r * 136 + col]);
        s += v; q += v * v;
    }
    float* red = (float*)wl;        // wl dead after GEMM2
    red[tid] = s;
    red[512 + tid] = q;
    __syncthreads();
    if (tid < 128) {
        float ts = red[tid] + red[128 + tid] + red[256 + tid] + red[384 + tid];
        float tq = red[512 + tid] + red[640 + tid] + red[768 + tid] + red[896 + tid];
        atomicAdd(&stats[tid], ts);
        atomicAdd(&stats[DD + tid], tq);
    }
}

// ---------------------------------------------------------------------------
// K5: out = h + relu(Y*scale + shift). BN math hoisted (column octet fixed).
// ---------------------------------------------------------------------------
__global__ __launch_bounds__(256) void bn_final_kernel(
    const unsigned short* __restrict__ Y, const float* __restrict__ h,
    const float* __restrict__ gamma, const float* __restrict__ beta,
    const float* __restrict__ stats, float* __restrict__ out)
{
    const float invN = 1.0f / (float)NN;
    int t0 = blockIdx.x * 256 + threadIdx.x;
    int c8 = t0 & 15;
    float sc[8], sh[8];
#pragma unroll
    for (int j = 0; j < 8; ++j) {
        int col = c8 * 8 + j;
        float mu = stats[col] * invN;
        float var = stats[DD + col] * invN - mu * mu;
        float s = rsqrtf(var + BN_EPS) * gamma[col];
        sc[j] = s;
        sh[j] = beta[col] - mu * s;
    }
    const short8* Y8 = (const short8*)Y;
    const float4* H4 = (const float4*)h;
    float4* O4 = (float4*)out;
    const int total = NN * 16;
    const int stride = BN_BLOCKS * 256;
    for (int i = t0; i < total; i += stride) {
        short8 u = Y8[i];
        float4 h0 = H4[2 * i], h1 = H4[2 * i + 1];
        float4 r0, r1;
        r0.x = h0.x + fmaxf(bf2f((unsigned short)u[0]) * sc[0] + sh[0], 0.f);
        r0.y = h0.y + fmaxf(bf2f((unsigned short)u[1]) * sc[1] + sh[1], 0.f);
        r0.z = h0.z + fmaxf(bf2f((unsigned short)u[2]) * sc[2] + sh[2], 0.f);
        r0.w = h0.w + fmaxf(bf2f((unsigned short)u[3]) * sc[3] + sh[3], 0.f);
        r1.x = h1.x + fmaxf(bf2f((unsigned short)u[4]) * sc[4] + sh[4], 0.f);
        r1.y = h1.y + fmaxf(bf2f((unsigned short)u[5]) * sc[5] + sh[5], 0.f);
        r1.z = h1.z + fmaxf(bf2f((unsigned short)u[6]) * sc[6] + sh[6], 0.f);
        r1.w = h1.w + fmaxf(bf2f((unsigned short)u[7]) * sc[7] + sh[7], 0.f);
        O4[2 * i] = r0;
        O4[2 * i + 1] = r1;
    }
}

// ---------------------------------------------------------------------------
extern "C" void kernel_launch(void* const* d_in, const int* in_sizes, int n_in,
                              void* d_out, int out_size, void* d_ws, size_t ws_size,
                              hipStream_t stream)
{
    const float* h     = (const float*)d_in[0];
    const int*   src   = (const int*)d_in[1];
    const int*   dst   = (const int*)d_in[2];
    const float* eps   = (const float*)d_in[3];
    const float* W1    = (const float*)d_in[4];
    const float* b1    = (const float*)d_in[5];
    const float* W2    = (const float*)d_in[6];
    const float* b2    = (const float*)d_in[7];
    const float* gamma = (const float*)d_in[8];
    const float* beta  = (const float*)d_in[9];
    float* out = (float*)d_out;

    char* w = (char*)d_ws;
    size_t o = 0;
    float* stats    = (float*)(w + o); o += 256 * 4;                 // memset
    int* scnt       = (int*)(w + o); o += 256 * 4;                   // memset
    unsigned short* W1t = (unsigned short*)(w + o); o += (size_t)DD * DD * 2;
    unsigned short* W2t = (unsigned short*)(w + o); o += (size_t)DD * DD * 2;
    int2* off2      = (int2*)(w + o); o += (size_t)NSB * SBSZ * 8;   // 802816
    int* sbuf       = (int*)(w + o); o += (size_t)NSB * CAPS * 4;    // 7.2 MB
    unsigned short* xb  = (unsigned short*)(w + o); o += (size_t)NN * DD * 2;
    unsigned short* hb  = (unsigned short*)(w + o); o += (size_t)NN * DD * 2;
    const int use_hb = (ws_size >= o) ? 1 : 0;  // launch-constant

    // 0. zero stats + super-bucket cursors
    hipMemsetAsync(stats, 0, 512 * sizeof(int), stream);

    // 1. radix scatter (512 blocks) + W transpose (64 blocks)
    prep_scatter_kernel<<<GRID_PS, 256, 0, stream>>>(
        W1, W2, W1t, W2t, src, dst, scnt, sbuf);

    // 2. per-super-bucket CSR permute (196 blocks) + h->bf16 copy (128 blocks)
    permute_copy_kernel<<<NSB + COPYBLKS, 1024, 0, stream>>>(
        scnt, sbuf, off2, h, hb, use_hb);

    // 3. gather (single dispatch, R11-proven config)
    if (use_hb)
        gather_bf16_kernel<<<(NN + 15) / 16, 256, 0, stream>>>(h, hb, eps, off2, sbuf, xb);
    else
        gather_f32_kernel<<<(NN + 15) / 16, 256, 0, stream>>>(h, eps, off2, sbuf, xb);

    // 4. fused 2-layer MLP + BN stats (128-row / 512-thread tile)
    size_t gemm_lds = 69632;
    mlp_fused_kernel<<<(NN + 127) / 128, 512, gemm_lds, stream>>>(
        xb, W1t, W2t, b1, b2, xb, stats);

    // 5. out = h + relu(BN(y2))
    bn_final_kernel<<<BN_BLOCKS, 256, 0, stream>>>(xb, h, gamma, beta, stats, out);
}